// Round 13
// baseline (142.687 us; speedup 1.0000x reference)
//
#include <hip/hip_runtime.h>
#include <stdint.h>

// Quant3Linear GEMV: y = x @ (scales.T * unpack3(qweight) - zeros.T) + bias
//   x: (1, 8192) f32 | qweight: (768, 28672) i32 | scales,zeros: (28672,1) | bias: (28672,)
// Decomposition: y[o] = scales[o]*dot(x, q[:,o]) - zeros[o]*sum(x) + bias[o]
//
// R13: SGPR-x. Four dot variants (cvt/pk/magic/scalar-magic) all ran at the
// same ~27-30us (R0-R12) -> the VALU bloat (eff. ~7 insts/elem from R11's
// VALUBusy*dur) is NOT in the unpack core; the shared suspect is the x path
// (LDS stage + 8 ds_read_b128/group + float4->reg unpack). x is WAVE-UNIFORM:
// load each group's 32 x floats via uniform-address loads (block-uniform
// const __restrict__ ptr -> s_load_dwordx16, SMEM) so the fma is
// v_fmac_f32 acc, s_x, v_mg (legal: 1 SGPR read). Magic base changed to
// 2.0f (INLINE constant, unlike 1.0f's 0x3F800000... which is inline too,
// but 8*x prescale would need VALU): u = shift|and 0x700000|2.0 -> 2 + c/4
// exactly, single v_and_or_b32 (sMask + inline base). Algebra:
//   acc = 2*S_range + dot/4  ->  y = 4*sc*acc - (8*sc + zr)*S + bias
// (same correction shape as R5/R12, numerically validated). qweight loop,
// atomics, grid: byte-identical to R12 -> single-variable A/B on the x path.
// History: latency/TLP dead (R1,R3,R11); balance dead (R6); memory dead
//   (R10 T_hot==T_cold, R11 27% HBM); fences toxic (R8); coop fails (R7);
//   dot restructures x4 neutral (R0/R4/R5/R12).

constexpr int O_FEAT  = 28672;
constexpr int IN_FEAT = 8192;
constexpr int NGROUP  = IN_FEAT / 32;   // 256 groups (3 packed int32 rows each)
constexpr int SPLIT   = 32;             // split-K factor
constexpr int GPB     = NGROUP / SPLIT; // 8 groups per thread
constexpr int O4      = O_FEAT / 4;     // uint4 columns per packed row
constexpr int NBX     = O4 / 64;        // 112 column groups (256 cols each)

// 3-bit field at bit sh of w -> float(2 + c/4): shift field into mantissa
// bits [20:23) of 2.0f (ULP of [2,4) is 2^-22; c<<20 = c/4). 2.0 is an
// inline constant -> single v_and_or_b32 with SGPR mask + inline base.
__device__ __forceinline__ float mg2(uint32_t w, int sh) {
  uint32_t u = (sh < 20) ? ((w << (20 - sh)) & 0x00700000u)
                         : ((w >> (sh - 20)) & 0x00700000u);
  return __uint_as_float(u | 0x40000000u);
}

// Unpack one column-group (32 3-bit codes in w0,w1,w2; GPTQ packing:
// e0..9 @ w0 bits 3j; e10 split w0/w1; e11..20 @ w1 bits 3j+1; e21 split
// w1/w2; e22..31 @ w2 bits 3j+2) and accumulate dot with uniform xv
// (SGPR-resident). 3 VALU/element: shift, and_or, fmac. 3 chains/column.
__device__ __forceinline__ void dot_group_sg(uint32_t w0, uint32_t w1, uint32_t w2,
                                             const float xv[32], float& acc) {
  float a0 = acc, a1 = 0.f, a2 = 0.f;
  #pragma unroll
  for (int j = 0; j < 10; ++j) a0 = fmaf(xv[j], mg2(w0, 3 * j), a0);
  { // e10 = (w0>>30)|((w1&1)<<2)
    uint32_t u = (((w0 >> 10) & 0x00300000u) | 0x40000000u) | ((w1 << 22) & 0x00400000u);
    a0 = fmaf(xv[10], __uint_as_float(u), a0);
  }
  #pragma unroll
  for (int j = 0; j < 10; ++j) a1 = fmaf(xv[11 + j], mg2(w1, 3 * j + 1), a1);
  { // e21 = (w1>>31)|((w2&3)<<1)
    uint32_t u = (((w1 >> 11) & 0x00100000u) | 0x40000000u) | ((w2 << 21) & 0x00600000u);
    a1 = fmaf(xv[21], __uint_as_float(u), a1);
  }
  #pragma unroll
  for (int j = 0; j < 10; ++j) a2 = fmaf(xv[22 + j], mg2(w2, 3 * j + 2), a2);
  acc = a0 + (a1 + a2);
}

__global__ __launch_bounds__(64) void q3_onepass(const float* __restrict__ x,
                                                 const uint4* __restrict__ qw4,
                                                 const float* __restrict__ scales,
                                                 const float* __restrict__ zeros,
                                                 const float* __restrict__ bias,
                                                 float* __restrict__ out) {
  const int tcol4 = blockIdx.x * 64 + threadIdx.x;   // index in units of 4 columns
  const int g0    = blockIdx.y * GPB;
  const uint4* qp = qw4 + (size_t)(3 * g0) * O4 + tcol4;
  const float* xb = x + g0 * 32;                     // block-uniform

  float acc0 = 0.f, acc1 = 0.f, acc2 = 0.f, acc3 = 0.f;

  // Rolled loop, depth-1 qweight prefetch (last iter re-loads own rows: L1 hit).
  uint4 na = qp[0], nb = qp[O4], nc = qp[2 * O4];
  for (int g = 0; g < GPB; ++g) {
    const uint4 wa = na, wb = nb, wc = nc;
    qp += (g < GPB - 1) ? 3 * O4 : 0;
    na = qp[0]; nb = qp[O4]; nc = qp[2 * O4];

    // 32 wave-uniform x values: uniform-address loads -> s_load (SMEM),
    // consumed directly as the SGPR operand of v_fmac.
    float xv[32];
    #pragma unroll
    for (int j = 0; j < 32; ++j) xv[j] = xb[g * 32 + j];

    dot_group_sg(wa.x, wb.x, wc.x, xv, acc0);  // 4 cols x 3 chains = 12-deep ILP
    dot_group_sg(wa.y, wb.y, wc.y, xv, acc1);
    dot_group_sg(wa.z, wb.z, wc.z, xv, acc2);
    dot_group_sg(wa.w, wb.w, wc.w, xv, acc3);
  }

  // acc = 2*S_range + dot_range/4 per column -> multiply by 4*scales here;
  // the 8*scales*S magic bias is cancelled in the by==0 correction below.
  const float4 sc = reinterpret_cast<const float4*>(scales)[tcol4];
  float4 contrib;
  contrib.x = 4.f * sc.x * acc0;
  contrib.y = 4.f * sc.y * acc1;
  contrib.z = 4.f * sc.z * acc2;
  contrib.w = 4.f * sc.w * acc3;

  if (blockIdx.y == 0) {
    // Fold in bias - (8*scales + zeros) * S.
    float s = 0.f;
    const float4* xall = reinterpret_cast<const float4*>(x);
    #pragma unroll
    for (int i = 0; i < (IN_FEAT / 4) / 64; ++i) {   // 32 float4 per lane
      float4 t = xall[i * 64 + threadIdx.x];
      s += (t.x + t.y) + (t.z + t.w);
    }
    #pragma unroll
    for (int off = 32; off > 0; off >>= 1) s += __shfl_xor(s, off, 64);
    const float S = s;                               // all lanes hold the total
    const float4 zr = reinterpret_cast<const float4*>(zeros)[tcol4];
    const float4 bi = reinterpret_cast<const float4*>(bias)[tcol4];
    contrib.x += bi.x - (8.f * sc.x + zr.x) * S;
    contrib.y += bi.y - (8.f * sc.y + zr.y) * S;
    contrib.z += bi.z - (8.f * sc.z + zr.z) * S;
    contrib.w += bi.w - (8.f * sc.w + zr.w) * S;
  }

  float* op = out + 4 * (size_t)tcol4;
  atomicAdd(op + 0, contrib.x);
  atomicAdd(op + 1, contrib.y);
  atomicAdd(op + 2, contrib.z);
  atomicAdd(op + 3, contrib.w);
}

extern "C" void kernel_launch(void* const* d_in, const int* in_sizes, int n_in,
                              void* d_out, int out_size, void* d_ws, size_t ws_size,
                              hipStream_t stream) {
  const float* x      = (const float*)d_in[0];
  const uint4* qw4    = (const uint4*)d_in[1];
  const float* scales = (const float*)d_in[2];
  const float* zeros  = (const float*)d_in[3];
  const float* bias   = (const float*)d_in[4];
  float*       out    = (float*)d_out;

  q3_onepass<<<dim3(NBX, SPLIT), dim3(64), 0, stream>>>(x, qw4, scales, zeros,
                                                        bias, out);
}